// Round 5
// baseline (505.047 us; speedup 1.0000x reference)
//
#include <hip/hip_runtime.h>
#include <hip/hip_bf16.h>
#include <math.h>

#define NS 255
#define NB 64
#define NE 200
#define NH 300
#define TS 2048          // shorts per 4KB tile (64 rows x 32 k)
#define HTS 1024         // shorts per half tile (32 rows)
#define GRID 256

// ws layout (bytes):
//  HbfT  [255][10][TS] bf16 tiled/swizzled  @ 0           (10,444,800)
//  Cf16  [255][10][TS] fp16 tiled/swizzled  @ 10,444,800  (10,444,800)
//  AembT [255][7][TS] bf16 tiled/swizzled   @ 20,889,600  ( 7,311,360)
//  BW    [4][5][17][TS] bf16 tiled/swizzled @ 28,200,960  ( 1,392,640)
//  ctr   u32 grid-sync counter              @ 29,593,600
//  end 29,593,604 (< 39,168,064 proven available)

typedef __attribute__((ext_vector_type(8))) short short8;
typedef __attribute__((ext_vector_type(4))) float f32x4;

__device__ __forceinline__ float sigmoidf_(float x) { return 1.0f / (1.0f + __expf(-x)); }
__device__ __forceinline__ unsigned short f2bf(float v) {
    union { __hip_bfloat16 b; unsigned short u; } cv; cv.b = __float2bfloat16(v); return cv.u;
}
__device__ __forceinline__ float bf2f(unsigned short u) {
    union { unsigned short u; __hip_bfloat16 b; } cv; cv.u = u; return __bfloat162float(cv.b);
}
__device__ __forceinline__ unsigned short f2h(float v) {
    union { _Float16 h; unsigned short u; } cv; cv.h = (_Float16)v; return cv.u;
}
__device__ __forceinline__ float h2f(unsigned short u) {
    union { unsigned short u; _Float16 h; } cv; cv.u = u; return (float)cv.h;
}
__device__ __forceinline__ int swz(int row, int kk) {
    int g = (kk >> 3) ^ ((row >> 1) & 3);
    return ((row << 2) + g) * 8 + (kk & 7);
}
// device-scope (sc1) 2-byte store: write-through past the non-coherent
// per-XCD L2 so consumers on any XCD read fresh data from the coherence
// point after the grid barrier. Correctness independent of XCD mapping.
__device__ __forceinline__ void st_agent(unsigned short* p, unsigned short v) {
    __hip_atomic_store(p, v, __ATOMIC_RELAXED, __HIP_MEMORY_SCOPE_AGENT);
}

// ---------------- prep: pre-tile weights + embeddings (R8-proven) -----------
__global__ __launch_bounds__(256) void prep_kernel(
    const float* __restrict__ U_iou, const float* __restrict__ U_f,
    const float* __restrict__ W_iou, const float* __restrict__ W_f,
    const float* __restrict__ embed, const int* __restrict__ x,
    unsigned short* __restrict__ BW, unsigned short* __restrict__ AembT,
    unsigned int* __restrict__ ctr)
{
    if (blockIdx.x == 0 && threadIdx.x == 0) *ctr = 0;   // re-arm grid sync
    const int gBW = 4 * 5 * 17 * 256;   // 87040 granules of 8 shorts
    const int gAe = NS * 7 * 256;       // 456960
    int total = gBW + gAe;
    int stride = gridDim.x * blockDim.x;
    for (int gi = blockIdx.x * blockDim.x + threadIdx.x; gi < total; gi += stride) {
        unsigned short st[8];
        if (gi < gBW) {
            int gg = gi & 255, tile = gi >> 8;
            int row = gg >> 2, pos = gg & 3;
            int kk0 = (pos ^ ((row >> 1) & 3)) << 3;
            int c = tile % 17, t2 = tile / 17;
            int s = t2 % 5, g4 = t2 / 5;
            int j = s * 64 + row;
#pragma unroll
            for (int u = 0; u < 8; ++u) {
                int kk = kk0 + u; float v = 0.f;
                if (c < 7) {
                    int k = c * 32 + kk;
                    if (j < NH && k < NE)
                        v = (g4 < 3) ? W_iou[k * 900 + g4 * NH + j] : W_f[k * NH + j];
                } else {
                    int k = (c - 7) * 32 + kk;
                    if (j < NH && k < NH)
                        v = (g4 < 3) ? U_iou[k * 900 + g4 * NH + j] : U_f[k * NH + j];
                }
                st[u] = f2bf(v);
            }
            *(short8*)(BW + (size_t)tile * TS + (row * 4 + pos) * 8) = *(short8*)st;
        } else {
            int gi2 = gi - gBW;
            int gg = gi2 & 255, tile = gi2 >> 8;
            int row = gg >> 2, pos = gg & 3;
            int kk0 = (pos ^ ((row >> 1) & 3)) << 3;
            int c = tile % 7, node = tile / 7;
            int k0 = c * 32 + kk0;
            const float* er = embed + (size_t)x[node * NB + row] * NE;
#pragma unroll
            for (int u = 0; u < 8; ++u)
                st[u] = (k0 + u < NE) ? f2bf(er[k0 + u]) : (unsigned short)0;
            *(short8*)(AembT + (size_t)tile * TS + (row * 4 + pos) * 8) = *(short8*)st;
        }
    }
}

// chunk loop, 32-row half: A frags 2, B frags 4, 8 MFMA; A-stride templated
template<int NCH, int SA>
__device__ __forceinline__ void gemm2(f32x4 acc[4][2],
    const unsigned short* __restrict__ A, const unsigned short* __restrict__ B)
{
#pragma unroll
    for (int c = 0; c < NCH; ++c) {
        const unsigned short* At = A + c * SA;
        const unsigned short* Bt = B + c * TS;
        short8 a0 = *(const short8*)(At);
        short8 a1 = *(const short8*)(At + 512);
#pragma unroll
        for (int t = 0; t < 4; ++t) {
            short8 b = *(const short8*)(Bt + t * 512);
            acc[t][0] = __builtin_amdgcn_mfma_f32_16x16x32_bf16(a0, b, acc[t][0], 0, 0, 0);
            acc[t][1] = __builtin_amdgcn_mfma_f32_16x16x32_bf16(a1, b, acc[t][1], 0, 0, 0);
        }
    }
}
// full-M chunk loop (leaf): A frags 4, 16 MFMA (R7/R8-proven)
template<int NCH>
__device__ __forceinline__ void gemm_f(f32x4 acc[4][4],
    const unsigned short* __restrict__ A, const unsigned short* __restrict__ B)
{
#pragma unroll
    for (int c = 0; c < NCH; ++c) {
        const unsigned short* At = A + c * TS;
        const unsigned short* Bt = B + c * TS;
        short8 a0 = *(const short8*)(At);
        short8 a1 = *(const short8*)(At + 512);
        short8 a2 = *(const short8*)(At + 1024);
        short8 a3 = *(const short8*)(At + 1536);
#pragma unroll
        for (int t = 0; t < 4; ++t) {
            short8 b = *(const short8*)(Bt + t * 512);
            acc[t][0] = __builtin_amdgcn_mfma_f32_16x16x32_bf16(a0, b, acc[t][0], 0, 0, 0);
            acc[t][1] = __builtin_amdgcn_mfma_f32_16x16x32_bf16(a1, b, acc[t][1], 0, 0, 0);
            acc[t][2] = __builtin_amdgcn_mfma_f32_16x16x32_bf16(a2, b, acc[t][2], 0, 0, 0);
            acc[t][3] = __builtin_amdgcn_mfma_f32_16x16x32_bf16(a3, b, acc[t][3], 0, 0, 0);
        }
    }
}

// ---------------- grid sync: RMW-spin barrier -------------------------------
// Arrival: device-scope atomicAdd (coherence-point RMW). Spin: idempotent
// atomicCAS -- an RMW ALWAYS observes the coherence point, independent of
// how relaxed atomic LOADS are lowered (R1-R4 failure: load-spin never saw
// remote adds -> every barrier timed out -> stale-data results).
// __threadfence() before/after = device-scope release/acquire (wb/inv).
__device__ __forceinline__ void gsync(unsigned int* ctr, unsigned int target)
{
    __syncthreads();                       // all block stores vmcnt-drained
    if (threadIdx.x == 0) {
        __threadfence();                   // release: flush anything dirty
        atomicAdd(ctr, 1u);                // arrive (device-scope RMW)
        int it = 0;
        while (atomicCAS(ctr, 0xFFFFFFFFu, 0xFFFFFFFFu) < target) {
            __builtin_amdgcn_s_sleep(8);
            if (++it > (1 << 17)) break;   // safety valve: never hang
        }
        __threadfence();                   // acquire: inv stale lines
    }
    __syncthreads();
}

// ---------------- one internal-level task (p, s, half), 5 waves -------------
__device__ __forceinline__ void level_body(int p, int s, int half,
    const unsigned short* __restrict__ AembT, const unsigned short* __restrict__ BW,
    const float* __restrict__ b_iou, const float* __restrict__ b_f,
    unsigned short* __restrict__ HbfT, unsigned short* __restrict__ Cg,
    unsigned short* sm)
{
    // Entry barrier: when a block runs >1 task per phase, the next task's
    // LDS staging must not overlap straggler waves still reading sm in the
    // previous task's epilogue.
    __syncthreads();

    int tid = threadIdx.x;
    int w = tid >> 6, lane = tid & 63, ln = lane & 15, quad = lane >> 4;
    int l = 2 * p + 1, r = 2 * p + 2;
    int bsel = (w < 4) ? w : 3;
    int gq = (quad ^ ((ln >> 1) & 3)) * 8;
    int offA = (half * 32 + ln) * 32 + gq;   // global A (emb tiles)
    int offL = ln * 32 + gq;                 // LDS A within half-tile
    int offB = ln * 32 + gq;

    // burst-stage: slots 0..9 Hl, 10..19 Hr, 20..21 Cl(2s,2s+1), 22..23 Cr
    for (int sidx = w; sidx < 24; sidx += 5) {
        const unsigned short* gsrc;
        if (sidx < 20) {
            int node = (sidx < 10) ? l : r;
            int tt = (sidx < 10) ? sidx : sidx - 10;
            gsrc = HbfT + ((size_t)node * 10 + tt) * TS + half * HTS;
        } else {
            int ii = sidx - 20;
            int node = (ii < 2) ? l : r;
            gsrc = Cg + ((size_t)node * 10 + 2 * s + (ii & 1)) * TS + half * HTS;
        }
        unsigned short* ldst = sm + sidx * HTS;
#pragma unroll
        for (int u = 0; u < 2; ++u)
            __builtin_amdgcn_global_load_lds(
                (const __attribute__((address_space(1))) unsigned short*)(gsrc + u * 512 + lane * 8),
                (__attribute__((address_space(3))) unsigned short*)(ldst + u * 512 + lane * 8),
                16, 0, 0);
    }

    f32x4 acc[4][2];
#pragma unroll
    for (int t = 0; t < 4; ++t)
#pragma unroll
        for (int q = 0; q < 2; ++q) acc[t][q] = (f32x4){0.f, 0.f, 0.f, 0.f};

    // emb contribution while the LDS DMA is in flight (A and B L2-warm)
    const unsigned short* Bsrc = BW + (size_t)(bsel * 5 + s) * 17 * TS;
    const unsigned short* Ae = AembT + (size_t)p * 7 * TS;
    gemm2<7, TS>(acc, Ae + offA, Bsrc + offB);

    __syncthreads();   // staging complete (vmcnt 0)

    const unsigned short* BH = Bsrc + 7 * TS + offB;
    if (w < 3) {
        gemm2<10, HTS>(acc, sm + offL, BH);             // Hl
        gemm2<10, HTS>(acc, sm + 10 * HTS + offL, BH);  // Hr
    } else if (w == 3) {
        gemm2<10, HTS>(acc, sm + offL, BH);
    } else {
        gemm2<10, HTS>(acc, sm + 10 * HTS + offL, BH);
    }

    // epilogue: smf aliases slots 0..5 (A consumed); C stays in slots 20..23
    float* smf = (float*)sm;
    for (int t = 0; t < 4; ++t) {
        __syncthreads();
#pragma unroll
        for (int ms = 0; ms < 2; ++ms)
#pragma unroll
            for (int rr = 0; rr < 4; ++rr)
                smf[w * 544 + (ms * 16 + quad * 4 + rr) * 17 + ln] = acc[t][ms][rr];
        __syncthreads();
        for (int idx2 = tid; idx2 < 512; idx2 += 320) {
            int mm = idx2 >> 4, n = idx2 & 15;
            int gm = half * 32 + mm;
            int jj = s * 64 + t * 16 + n;
            bool ok = jj < NH;
            float pi = smf[0 * 544 + mm * 17 + n] + (ok ? b_iou[jj] : 0.f);
            float po = smf[1 * 544 + mm * 17 + n] + (ok ? b_iou[NH + jj] : 0.f);
            float pu = smf[2 * 544 + mm * 17 + n] + (ok ? b_iou[2 * NH + jj] : 0.f);
            float bj = ok ? b_f[jj] : 0.f;
            float fl = sigmoidf_(smf[3 * 544 + mm * 17 + n] + bj);
            float fr = sigmoidf_(smf[4 * 544 + mm * 17 + n] + bj);
            int xr = (mm >> 1) & 3;
            int cel = (mm * 4 + ((((t & 1) * 2) + (n >> 3)) ^ xr)) * 8 + (n & 7);
            int ts2 = t >> 1;
            float cl = h2f(sm[(20 + ts2) * HTS + cel]);
            float cr = h2f(sm[(22 + ts2) * HTS + cel]);
            float cc = sigmoidf_(pi) * tanhf(pu) + fl * cl + fr * cr;
            float hh = sigmoidf_(po) * tanhf(cc);
            size_t tbase = ((size_t)p * 10 + (jj >> 5)) * TS + swz(gm, jj & 31);
            if (ok) st_agent(Cg + tbase, f2h(cc));
            st_agent(HbfT + tbase, ok ? f2bf(hh) : (unsigned short)0);
        }
    }
}

// ---------------- leaf task (p, s): waves 0-2 compute i,o,u ------------------
// (Safe under task looping: no LDS touch before the t-loop's entry barrier.)
__device__ __forceinline__ void leaf_body(int p, int s,
    const unsigned short* __restrict__ AembT, const unsigned short* __restrict__ BW,
    const float* __restrict__ b_iou,
    unsigned short* __restrict__ HbfT, unsigned short* __restrict__ Cg,
    unsigned short* sm)
{
    int tid = threadIdx.x;
    int w = tid >> 6, lane = tid & 63, ln = lane & 15, quad = lane >> 4;
    int off = ln * 32 + (quad ^ ((ln >> 1) & 3)) * 8;
    int wb = (w < 3) ? w : 0;
    const unsigned short* Bsrc = BW + (size_t)(wb * 5 + s) * 17 * TS;
    const unsigned short* Ae = AembT + (size_t)p * 7 * TS;

    f32x4 acc[4][4];
    if (w < 3) {
#pragma unroll
        for (int t = 0; t < 4; ++t)
#pragma unroll
            for (int q = 0; q < 4; ++q) acc[t][q] = (f32x4){0.f, 0.f, 0.f, 0.f};
        gemm_f<7>(acc, Ae + off, Bsrc + off);
    }

    float* tf = (float*)sm;   // [3][64][16] = 12 KB, aliases LDS
    for (int t = 0; t < 4; ++t) {
        __syncthreads();
        if (w < 3)
#pragma unroll
            for (int ms = 0; ms < 4; ++ms)
#pragma unroll
                for (int rr = 0; rr < 4; ++rr)
                    tf[(w * 64 + ms * 16 + quad * 4 + rr) * 16 + ln] = acc[t][ms][rr];
        __syncthreads();
        for (int idx2 = tid; idx2 < 1024; idx2 += 320) {
            int mm = idx2 >> 4, n = idx2 & 15;
            int jj = s * 64 + t * 16 + n;
            bool ok = jj < NH;
            float pi = tf[(0 * 64 + mm) * 16 + n] + (ok ? b_iou[jj] : 0.f);
            float po = tf[(1 * 64 + mm) * 16 + n] + (ok ? b_iou[NH + jj] : 0.f);
            float pu = tf[(2 * 64 + mm) * 16 + n] + (ok ? b_iou[2 * NH + jj] : 0.f);
            float cc = sigmoidf_(pi) * tanhf(pu);
            float hh = sigmoidf_(po) * tanhf(cc);
            size_t tbase = ((size_t)p * 10 + (jj >> 5)) * TS + swz(mm, jj & 31);
            if (ok) st_agent(Cg + tbase, f2h(cc));
            st_agent(HbfT + tbase, ok ? f2bf(hh) : (unsigned short)0);
        }
    }
}

// ---------------- fused tree: leaf + 7 levels + out, one dispatch -----------
// 256 blocks x 320 threads, launch_bounds(320,2) -> VGPR cap 256 means at
// most 1 block/CU can be resident, and 256 CUs exist -> ALL blocks resident
// by construction (no packing assumptions). Grid sync via RMW-spin barrier.
__global__ __launch_bounds__(320, 2) void tree_kernel(
    const unsigned short* __restrict__ AembT, const unsigned short* __restrict__ BW,
    const float* __restrict__ b_iou, const float* __restrict__ b_f,
    unsigned short* __restrict__ HbfT, unsigned short* __restrict__ Cg,
    const float* __restrict__ W_out, const float* __restrict__ b_out,
    float* __restrict__ outp, unsigned int* __restrict__ ctr)
{
    __shared__ unsigned short sm[24 * HTS];   // 48 KB
    int bid = blockIdx.x;
    int tid = threadIdx.x;
    unsigned int tgt = GRID;

    // ---- leaf (level 7): 128 nodes x 5 strips = 640 tasks ------------------
    for (int T = bid; T < 640; T += GRID) {
        int xcd = T & 7, idx = T >> 3;
        leaf_body(127 + xcd * 16 + (idx & 15), idx >> 4,
                  AembT, BW, b_iou, HbfT, Cg, sm);
    }
    gsync(ctr, tgt); tgt += GRID;

    // ---- internal levels d=6..3: 80*(1<<(d-3)) tasks -----------------------
#pragma unroll 1
    for (int d = 6; d >= 3; --d) {
        int sh2 = d - 3;
        int ntask = 80 << sh2;
        for (int T = bid; T < ntask; T += GRID) {
            int xcd = T & 7, idx = T >> 3;
            int o = idx & ((1 << sh2) - 1);
            int rest = idx >> sh2;            // 0..9
            level_body((1 << d) - 1 + (xcd << sh2) + o, rest % 5, rest / 5,
                       AembT, BW, b_iou, b_f, HbfT, Cg, sm);
        }
        gsync(ctr, tgt); tgt += GRID;
    }

    // ---- tail levels d=2..0: 40/20/10 tasks --------------------------------
#pragma unroll 1
    for (int d = 2; d >= 0; --d) {
        int ntask = 10 << d;
        if (bid < ntask) {
            int rest = bid % 10;
            level_body((1 << d) - 1 + bid / 10, rest % 5, rest / 5,
                       AembT, BW, b_iou, b_f, HbfT, Cg, sm);
        }
        gsync(ctr, tgt); tgt += GRID;
    }

    // ---- root -> logits -> log_softmax (block 0, LDS-staged) ---------------
    if (bid != 0) return;
    {
        float* wsm = (float*)(sm + 20 * HTS); // after 40KB of root-H tiles
        for (int i = tid; i < 2560; i += 320) // 10 tiles x 256 granules
            *(short8*)(sm + i * 8) = *(const short8*)(HbfT + i * 8);
        for (int i = tid; i < 2 * NH; i += 320)
            wsm[i] = W_out[i];
        __syncthreads();
        if (tid < 64) {
            int b = tid;
            float l0 = 0.f, l1 = 0.f;
#pragma unroll 4
            for (int k = 0; k < NH; ++k) {
                float hk = bf2f(sm[(k >> 5) * TS + swz(b, k & 31)]);
                l0 += hk * wsm[2 * k];
                l1 += hk * wsm[2 * k + 1];
            }
            l0 += b_out[0];
            l1 += b_out[1];
            float mx = fmaxf(l0, l1);
            float lse = mx + logf(__expf(l0 - mx) + __expf(l1 - mx));
            outp[b * 2 + 0] = l0 - lse;
            outp[b * 2 + 1] = l1 - lse;
        }
    }
}

extern "C" void kernel_launch(void* const* d_in, const int* in_sizes, int n_in,
                              void* d_out, int out_size, void* d_ws, size_t ws_size,
                              hipStream_t stream)
{
    const int*   x     = (const int*)d_in[0];
    const float* embed = (const float*)d_in[3];
    const float* W_iou = (const float*)d_in[4];
    const float* U_iou = (const float*)d_in[5];
    const float* b_iou = (const float*)d_in[6];
    const float* W_f   = (const float*)d_in[7];
    const float* U_f   = (const float*)d_in[8];
    const float* b_f   = (const float*)d_in[9];
    const float* W_out = (const float*)d_in[10];
    const float* b_out = (const float*)d_in[11];

    char* ws = (char*)d_ws;
    unsigned short* HbfT  = (unsigned short*)(ws + 0);
    unsigned short* Cg    = (unsigned short*)(ws + 10444800);
    unsigned short* AembT = (unsigned short*)(ws + 20889600);
    unsigned short* BW    = (unsigned short*)(ws + 28200960);
    unsigned int*   ctr   = (unsigned int*)(ws + 29593600);

    prep_kernel<<<4096, 256, 0, stream>>>(U_iou, U_f, W_iou, W_f, embed, x,
                                          BW, AembT, ctr);
    tree_kernel<<<GRID, 320, 0, stream>>>(AembT, BW, b_iou, b_f, HbfT, Cg,
                                          W_out, b_out, (float*)d_out, ctr);
}

// Round 7
// 402.079 us; speedup vs baseline: 1.2561x; 1.2561x over previous
//
#include <hip/hip_runtime.h>
#include <hip/hip_bf16.h>
#include <math.h>

#define NS 255
#define NB 64
#define NE 200
#define NH 300
#define TS 2048          // shorts per 4KB tile (64 rows x 32 k)
#define HTS 1024         // shorts per half tile (32 rows)
#define GRID 256

// ws layout (bytes):
//  HbfT  [255][10][TS] bf16 tiled/swizzled  @ 0           (10,444,800)
//  Cf16  [255][10][TS] fp16 tiled/swizzled  @ 10,444,800  (10,444,800)
//  AembT [255][7][TS] bf16 tiled/swizzled   @ 20,889,600  ( 7,311,360)
//  BW    [4][5][17][TS] bf16 tiled/swizzled @ 28,200,960  ( 1,392,640)
//  ctr   u32 grid-sync counter              @ 29,593,600
//  end 29,593,604 (< 39,168,064 proven available)

typedef __attribute__((ext_vector_type(8))) short short8;
typedef __attribute__((ext_vector_type(4))) float f32x4;

__device__ __forceinline__ float sigmoidf_(float x) { return 1.0f / (1.0f + __expf(-x)); }
__device__ __forceinline__ unsigned short f2bf(float v) {
    union { __hip_bfloat16 b; unsigned short u; } cv; cv.b = __float2bfloat16(v); return cv.u;
}
__device__ __forceinline__ float bf2f(unsigned short u) {
    union { unsigned short u; __hip_bfloat16 b; } cv; cv.u = u; return __bfloat162float(cv.b);
}
__device__ __forceinline__ unsigned short f2h(float v) {
    union { _Float16 h; unsigned short u; } cv; cv.h = (_Float16)v; return cv.u;
}
__device__ __forceinline__ float h2f(unsigned short u) {
    union { unsigned short u; _Float16 h; } cv; cv.u = u; return (float)cv.h;
}
__device__ __forceinline__ int swz(int row, int kk) {
    int g = (kk >> 3) ^ ((row >> 1) & 3);
    return ((row << 2) + g) * 8 + (kk & 7);
}

// ---------------- prep: pre-tile weights + embeddings (R8-proven) -----------
__global__ __launch_bounds__(256) void prep_kernel(
    const float* __restrict__ U_iou, const float* __restrict__ U_f,
    const float* __restrict__ W_iou, const float* __restrict__ W_f,
    const float* __restrict__ embed, const int* __restrict__ x,
    unsigned short* __restrict__ BW, unsigned short* __restrict__ AembT,
    unsigned int* __restrict__ ctr)
{
    if (blockIdx.x == 0 && threadIdx.x == 0) *ctr = 0;   // re-arm grid sync
    const int gBW = 4 * 5 * 17 * 256;   // 87040 granules of 8 shorts
    const int gAe = NS * 7 * 256;       // 456960
    int total = gBW + gAe;
    int stride = gridDim.x * blockDim.x;
    for (int gi = blockIdx.x * blockDim.x + threadIdx.x; gi < total; gi += stride) {
        unsigned short st[8];
        if (gi < gBW) {
            int gg = gi & 255, tile = gi >> 8;
            int row = gg >> 2, pos = gg & 3;
            int kk0 = (pos ^ ((row >> 1) & 3)) << 3;
            int c = tile % 17, t2 = tile / 17;
            int s = t2 % 5, g4 = t2 / 5;
            int j = s * 64 + row;
#pragma unroll
            for (int u = 0; u < 8; ++u) {
                int kk = kk0 + u; float v = 0.f;
                if (c < 7) {
                    int k = c * 32 + kk;
                    if (j < NH && k < NE)
                        v = (g4 < 3) ? W_iou[k * 900 + g4 * NH + j] : W_f[k * NH + j];
                } else {
                    int k = (c - 7) * 32 + kk;
                    if (j < NH && k < NH)
                        v = (g4 < 3) ? U_iou[k * 900 + g4 * NH + j] : U_f[k * NH + j];
                }
                st[u] = f2bf(v);
            }
            *(short8*)(BW + (size_t)tile * TS + (row * 4 + pos) * 8) = *(short8*)st;
        } else {
            int gi2 = gi - gBW;
            int gg = gi2 & 255, tile = gi2 >> 8;
            int row = gg >> 2, pos = gg & 3;
            int kk0 = (pos ^ ((row >> 1) & 3)) << 3;
            int c = tile % 7, node = tile / 7;
            int k0 = c * 32 + kk0;
            const float* er = embed + (size_t)x[node * NB + row] * NE;
#pragma unroll
            for (int u = 0; u < 8; ++u)
                st[u] = (k0 + u < NE) ? f2bf(er[k0 + u]) : (unsigned short)0;
            *(short8*)(AembT + (size_t)tile * TS + (row * 4 + pos) * 8) = *(short8*)st;
        }
    }
}

// chunk loop, 32-row half: A frags 2, B frags 4, 8 MFMA; A-stride templated
template<int NCH, int SA>
__device__ __forceinline__ void gemm2(f32x4 acc[4][2],
    const unsigned short* __restrict__ A, const unsigned short* __restrict__ B)
{
#pragma unroll
    for (int c = 0; c < NCH; ++c) {
        const unsigned short* At = A + c * SA;
        const unsigned short* Bt = B + c * TS;
        short8 a0 = *(const short8*)(At);
        short8 a1 = *(const short8*)(At + 512);
#pragma unroll
        for (int t = 0; t < 4; ++t) {
            short8 b = *(const short8*)(Bt + t * 512);
            acc[t][0] = __builtin_amdgcn_mfma_f32_16x16x32_bf16(a0, b, acc[t][0], 0, 0, 0);
            acc[t][1] = __builtin_amdgcn_mfma_f32_16x16x32_bf16(a1, b, acc[t][1], 0, 0, 0);
        }
    }
}
// full-M chunk loop (leaf): A frags 4, 16 MFMA (R7/R8-proven)
template<int NCH>
__device__ __forceinline__ void gemm_f(f32x4 acc[4][4],
    const unsigned short* __restrict__ A, const unsigned short* __restrict__ B)
{
#pragma unroll
    for (int c = 0; c < NCH; ++c) {
        const unsigned short* At = A + c * TS;
        const unsigned short* Bt = B + c * TS;
        short8 a0 = *(const short8*)(At);
        short8 a1 = *(const short8*)(At + 512);
        short8 a2 = *(const short8*)(At + 1024);
        short8 a3 = *(const short8*)(At + 1536);
#pragma unroll
        for (int t = 0; t < 4; ++t) {
            short8 b = *(const short8*)(Bt + t * 512);
            acc[t][0] = __builtin_amdgcn_mfma_f32_16x16x32_bf16(a0, b, acc[t][0], 0, 0, 0);
            acc[t][1] = __builtin_amdgcn_mfma_f32_16x16x32_bf16(a1, b, acc[t][1], 0, 0, 0);
            acc[t][2] = __builtin_amdgcn_mfma_f32_16x16x32_bf16(a2, b, acc[t][2], 0, 0, 0);
            acc[t][3] = __builtin_amdgcn_mfma_f32_16x16x32_bf16(a3, b, acc[t][3], 0, 0, 0);
        }
    }
}

// ---------------- grid sync: RMW-spin barrier + agent fences ----------------
// R5-proven: the spin must be an RMW (atomicCAS). A relaxed atomic LOAD spin
// re-hits the same stale L2 line forever (no per-poll invalidate) -> R1-R4
// timeouts. With PLAIN epilogue stores (write-back, L2-coalescing), the
// fences carry coherence: __threadfence() release (wbl2: XCD L2 writeback)
// before arrival; acquire (inv) after departure. Every block fences ->
// every XCD flushes/invalidates -> independent of block->XCD mapping.
__device__ __forceinline__ void gsync(unsigned int* ctr, unsigned int target)
{
    __syncthreads();                       // all block stores vmcnt-drained
    if (threadIdx.x == 0) {
        __threadfence();                   // release: flush XCD L2 dirty lines
        atomicAdd(ctr, 1u);                // arrive (device-scope RMW)
        int it = 0;
        while (atomicCAS(ctr, 0xFFFFFFFFu, 0xFFFFFFFFu) < target) {
            if (++it < 3) __builtin_amdgcn_s_sleep(8);
            else          __builtin_amdgcn_s_sleep(64);   // backoff: cut CAS storm
            if (it > (1 << 17)) break;     // safety valve: never hang
        }
        __threadfence();                   // acquire: inv stale L1/L2 lines
    }
    __syncthreads();
}

// ---------------- one internal-level task (p, s, half), 5 waves -------------
__device__ __forceinline__ void level_body(int p, int s, int half,
    const unsigned short* __restrict__ AembT, const unsigned short* __restrict__ BW,
    const float* __restrict__ b_iou, const float* __restrict__ b_f,
    unsigned short* __restrict__ HbfT, unsigned short* __restrict__ Cg,
    unsigned short* sm)
{
    // Entry barrier: when a block runs >1 task per phase, the next task's
    // LDS staging must not overlap straggler waves still reading sm in the
    // previous task's epilogue.
    __syncthreads();

    int tid = threadIdx.x;
    int w = tid >> 6, lane = tid & 63, ln = lane & 15, quad = lane >> 4;
    int l = 2 * p + 1, r = 2 * p + 2;
    int bsel = (w < 4) ? w : 3;
    int gq = (quad ^ ((ln >> 1) & 3)) * 8;
    int offA = (half * 32 + ln) * 32 + gq;   // global A (emb tiles)
    int offL = ln * 32 + gq;                 // LDS A within half-tile
    int offB = ln * 32 + gq;

    // burst-stage: slots 0..9 Hl, 10..19 Hr, 20..21 Cl(2s,2s+1), 22..23 Cr
    for (int sidx = w; sidx < 24; sidx += 5) {
        const unsigned short* gsrc;
        if (sidx < 20) {
            int node = (sidx < 10) ? l : r;
            int tt = (sidx < 10) ? sidx : sidx - 10;
            gsrc = HbfT + ((size_t)node * 10 + tt) * TS + half * HTS;
        } else {
            int ii = sidx - 20;
            int node = (ii < 2) ? l : r;
            gsrc = Cg + ((size_t)node * 10 + 2 * s + (ii & 1)) * TS + half * HTS;
        }
        unsigned short* ldst = sm + sidx * HTS;
#pragma unroll
        for (int u = 0; u < 2; ++u)
            __builtin_amdgcn_global_load_lds(
                (const __attribute__((address_space(1))) unsigned short*)(gsrc + u * 512 + lane * 8),
                (__attribute__((address_space(3))) unsigned short*)(ldst + u * 512 + lane * 8),
                16, 0, 0);
    }

    f32x4 acc[4][2];
#pragma unroll
    for (int t = 0; t < 4; ++t)
#pragma unroll
        for (int q = 0; q < 2; ++q) acc[t][q] = (f32x4){0.f, 0.f, 0.f, 0.f};

    // emb contribution while the LDS DMA is in flight (A and B L2-warm)
    const unsigned short* Bsrc = BW + (size_t)(bsel * 5 + s) * 17 * TS;
    const unsigned short* Ae = AembT + (size_t)p * 7 * TS;
    gemm2<7, TS>(acc, Ae + offA, Bsrc + offB);

    __syncthreads();   // staging complete (vmcnt 0)

    const unsigned short* BH = Bsrc + 7 * TS + offB;
    if (w < 3) {
        gemm2<10, HTS>(acc, sm + offL, BH);             // Hl
        gemm2<10, HTS>(acc, sm + 10 * HTS + offL, BH);  // Hr
    } else if (w == 3) {
        gemm2<10, HTS>(acc, sm + offL, BH);
    } else {
        gemm2<10, HTS>(acc, sm + 10 * HTS + offL, BH);
    }

    // epilogue: smf aliases slots 0..5 (A consumed); C stays in slots 20..23
    float* smf = (float*)sm;
    for (int t = 0; t < 4; ++t) {
        __syncthreads();
#pragma unroll
        for (int ms = 0; ms < 2; ++ms)
#pragma unroll
            for (int rr = 0; rr < 4; ++rr)
                smf[w * 544 + (ms * 16 + quad * 4 + rr) * 17 + ln] = acc[t][ms][rr];
        __syncthreads();
        for (int idx2 = tid; idx2 < 512; idx2 += 320) {
            int mm = idx2 >> 4, n = idx2 & 15;
            int gm = half * 32 + mm;
            int jj = s * 64 + t * 16 + n;
            bool ok = jj < NH;
            float pi = smf[0 * 544 + mm * 17 + n] + (ok ? b_iou[jj] : 0.f);
            float po = smf[1 * 544 + mm * 17 + n] + (ok ? b_iou[NH + jj] : 0.f);
            float pu = smf[2 * 544 + mm * 17 + n] + (ok ? b_iou[2 * NH + jj] : 0.f);
            float bj = ok ? b_f[jj] : 0.f;
            float fl = sigmoidf_(smf[3 * 544 + mm * 17 + n] + bj);
            float fr = sigmoidf_(smf[4 * 544 + mm * 17 + n] + bj);
            int xr = (mm >> 1) & 3;
            int cel = (mm * 4 + ((((t & 1) * 2) + (n >> 3)) ^ xr)) * 8 + (n & 7);
            int ts2 = t >> 1;
            float cl = h2f(sm[(20 + ts2) * HTS + cel]);
            float cr = h2f(sm[(22 + ts2) * HTS + cel]);
            float cc = sigmoidf_(pi) * tanhf(pu) + fl * cl + fr * cr;
            float hh = sigmoidf_(po) * tanhf(cc);
            size_t tbase = ((size_t)p * 10 + (jj >> 5)) * TS + swz(gm, jj & 31);
            if (ok) Cg[tbase] = f2h(cc);               // plain: L2 write-back
            HbfT[tbase] = ok ? f2bf(hh) : (unsigned short)0;
        }
    }
}

// ---------------- leaf task (p, s): waves 0-2 compute i,o,u ------------------
// (Safe under task looping: no LDS touch before the t-loop's entry barrier.)
__device__ __forceinline__ void leaf_body(int p, int s,
    const unsigned short* __restrict__ AembT, const unsigned short* __restrict__ BW,
    const float* __restrict__ b_iou,
    unsigned short* __restrict__ HbfT, unsigned short* __restrict__ Cg,
    unsigned short* sm)
{
    int tid = threadIdx.x;
    int w = tid >> 6, lane = tid & 63, ln = lane & 15, quad = lane >> 4;
    int off = ln * 32 + (quad ^ ((ln >> 1) & 3)) * 8;
    int wb = (w < 3) ? w : 0;
    const unsigned short* Bsrc = BW + (size_t)(wb * 5 + s) * 17 * TS;
    const unsigned short* Ae = AembT + (size_t)p * 7 * TS;

    f32x4 acc[4][4];
    if (w < 3) {
#pragma unroll
        for (int t = 0; t < 4; ++t)
#pragma unroll
            for (int q = 0; q < 4; ++q) acc[t][q] = (f32x4){0.f, 0.f, 0.f, 0.f};
        gemm_f<7>(acc, Ae + off, Bsrc + off);
    }

    float* tf = (float*)sm;   // [3][64][16] = 12 KB, aliases LDS
    for (int t = 0; t < 4; ++t) {
        __syncthreads();
        if (w < 3)
#pragma unroll
            for (int ms = 0; ms < 4; ++ms)
#pragma unroll
                for (int rr = 0; rr < 4; ++rr)
                    tf[(w * 64 + ms * 16 + quad * 4 + rr) * 16 + ln] = acc[t][ms][rr];
        __syncthreads();
        for (int idx2 = tid; idx2 < 1024; idx2 += 320) {
            int mm = idx2 >> 4, n = idx2 & 15;
            int jj = s * 64 + t * 16 + n;
            bool ok = jj < NH;
            float pi = tf[(0 * 64 + mm) * 16 + n] + (ok ? b_iou[jj] : 0.f);
            float po = tf[(1 * 64 + mm) * 16 + n] + (ok ? b_iou[NH + jj] : 0.f);
            float pu = tf[(2 * 64 + mm) * 16 + n] + (ok ? b_iou[2 * NH + jj] : 0.f);
            float cc = sigmoidf_(pi) * tanhf(pu);
            float hh = sigmoidf_(po) * tanhf(cc);
            size_t tbase = ((size_t)p * 10 + (jj >> 5)) * TS + swz(mm, jj & 31);
            if (ok) Cg[tbase] = f2h(cc);
            HbfT[tbase] = ok ? f2bf(hh) : (unsigned short)0;
        }
    }
}

// ---------------- fused tree: leaf + 7 levels + out, one dispatch -----------
// 256 blocks x 320 threads, launch_bounds(320,2): at most 1 block/CU by
// VGPR (128 measured, R5) on 256 CUs -> ALL blocks resident by construction
// (R5-proven). Single variable vs R5: plain stores + fences (not st_agent).
__global__ __launch_bounds__(320, 2) void tree_kernel(
    const unsigned short* __restrict__ AembT, const unsigned short* __restrict__ BW,
    const float* __restrict__ b_iou, const float* __restrict__ b_f,
    unsigned short* __restrict__ HbfT, unsigned short* __restrict__ Cg,
    const float* __restrict__ W_out, const float* __restrict__ b_out,
    float* __restrict__ outp, unsigned int* __restrict__ ctr)
{
    __shared__ unsigned short sm[24 * HTS];   // 48 KB
    int bid = blockIdx.x;
    int tid = threadIdx.x;
    unsigned int tgt = GRID;

    // ---- leaf (level 7): 128 nodes x 5 strips = 640 tasks ------------------
    for (int T = bid; T < 640; T += GRID) {
        int xcd = T & 7, idx = T >> 3;
        leaf_body(127 + xcd * 16 + (idx & 15), idx >> 4,
                  AembT, BW, b_iou, HbfT, Cg, sm);
    }
    gsync(ctr, tgt); tgt += GRID;

    // ---- internal levels d=6..3: 80*(1<<(d-3)) tasks -----------------------
#pragma unroll 1
    for (int d = 6; d >= 3; --d) {
        int sh2 = d - 3;
        int ntask = 80 << sh2;
        for (int T = bid; T < ntask; T += GRID) {
            int xcd = T & 7, idx = T >> 3;
            int o = idx & ((1 << sh2) - 1);
            int rest = idx >> sh2;            // 0..9
            level_body((1 << d) - 1 + (xcd << sh2) + o, rest % 5, rest / 5,
                       AembT, BW, b_iou, b_f, HbfT, Cg, sm);
        }
        gsync(ctr, tgt); tgt += GRID;
    }

    // ---- tail levels d=2..0: 40/20/10 tasks --------------------------------
#pragma unroll 1
    for (int d = 2; d >= 0; --d) {
        int ntask = 10 << d;
        if (bid < ntask) {
            int rest = bid % 10;
            level_body((1 << d) - 1 + bid / 10, rest % 5, rest / 5,
                       AembT, BW, b_iou, b_f, HbfT, Cg, sm);
        }
        gsync(ctr, tgt); tgt += GRID;
    }

    // ---- root -> logits -> log_softmax (block 0, LDS-staged) ---------------
    if (bid != 0) return;
    {
        float* wsm = (float*)(sm + 20 * HTS); // after 40KB of root-H tiles
        for (int i = tid; i < 2560; i += 320) // 10 tiles x 256 granules
            *(short8*)(sm + i * 8) = *(const short8*)(HbfT + i * 8);
        for (int i = tid; i < 2 * NH; i += 320)
            wsm[i] = W_out[i];
        __syncthreads();
        if (tid < 64) {
            int b = tid;
            float l0 = 0.f, l1 = 0.f;
#pragma unroll 4
            for (int k = 0; k < NH; ++k) {
                float hk = bf2f(sm[(k >> 5) * TS + swz(b, k & 31)]);
                l0 += hk * wsm[2 * k];
                l1 += hk * wsm[2 * k + 1];
            }
            l0 += b_out[0];
            l1 += b_out[1];
            float mx = fmaxf(l0, l1);
            float lse = mx + logf(__expf(l0 - mx) + __expf(l1 - mx));
            outp[b * 2 + 0] = l0 - lse;
            outp[b * 2 + 1] = l1 - lse;
        }
    }
}

extern "C" void kernel_launch(void* const* d_in, const int* in_sizes, int n_in,
                              void* d_out, int out_size, void* d_ws, size_t ws_size,
                              hipStream_t stream)
{
    const int*   x     = (const int*)d_in[0];
    const float* embed = (const float*)d_in[3];
    const float* W_iou = (const float*)d_in[4];
    const float* U_iou = (const float*)d_in[5];
    const float* b_iou = (const float*)d_in[6];
    const float* W_f   = (const float*)d_in[7];
    const float* U_f   = (const float*)d_in[8];
    const float* b_f   = (const float*)d_in[9];
    const float* W_out = (const float*)d_in[10];
    const float* b_out = (const float*)d_in[11];

    char* ws = (char*)d_ws;
    unsigned short* HbfT  = (unsigned short*)(ws + 0);
    unsigned short* Cg    = (unsigned short*)(ws + 10444800);
    unsigned short* AembT = (unsigned short*)(ws + 20889600);
    unsigned short* BW    = (unsigned short*)(ws + 28200960);
    unsigned int*   ctr   = (unsigned int*)(ws + 29593600);

    prep_kernel<<<4096, 256, 0, stream>>>(U_iou, U_f, W_iou, W_f, embed, x,
                                          BW, AembT, ctr);
    tree_kernel<<<GRID, 320, 0, stream>>>(AembT, BW, b_iou, b_f, HbfT, Cg,
                                          W_out, b_out, (float*)d_out, ctr);
}

// Round 8
// 393.237 us; speedup vs baseline: 1.2843x; 1.0225x over previous
//
#include <hip/hip_runtime.h>
#include <hip/hip_bf16.h>
#include <math.h>

#define NS 255
#define NB 64
#define NE 200
#define NH 300
#define TS 2048          // shorts per 4KB tile (64 rows x 32 k)
#define HTS 1024         // shorts per half tile (32 rows)
#define NBLK 256         // blocks; 1 block/CU on 256 CUs -> resident by construction

// ws layout (bytes):
//  HbfT  [255][10][TS] bf16 tiled/swizzled  @ 0           (10,444,800)
//  Cf16  [255][10][TS] fp16 tiled/swizzled  @ 10,444,800  (10,444,800)
//  AembT [255][7][TS] bf16 tiled/swizzled   @ 20,889,600  ( 7,311,360)
//  BW    [4][5][17][TS] bf16 tiled/swizzled @ 28,200,960  ( 1,392,640)
//  slots 16 x u32, 64B-padded barrier slots @ 29,593,600  ( 1,024 )
//  end 29,594,624 (< 39,168,064 proven available)

typedef __attribute__((ext_vector_type(8))) short short8;
typedef __attribute__((ext_vector_type(4))) float f32x4;

__device__ __forceinline__ float sigmoidf_(float x) { return 1.0f / (1.0f + __expf(-x)); }
__device__ __forceinline__ unsigned short f2bf(float v) {
    union { __hip_bfloat16 b; unsigned short u; } cv; cv.b = __float2bfloat16(v); return cv.u;
}
__device__ __forceinline__ float bf2f(unsigned short u) {
    union { unsigned short u; __hip_bfloat16 b; } cv; cv.u = u; return __bfloat162float(cv.b);
}
__device__ __forceinline__ unsigned short f2h(float v) {
    union { _Float16 h; unsigned short u; } cv; cv.h = (_Float16)v; return cv.u;
}
__device__ __forceinline__ float h2f(unsigned short u) {
    union { unsigned short u; _Float16 h; } cv; cv.u = u; return (float)cv.h;
}
__device__ __forceinline__ int swz(int row, int kk) {
    int g = (kk >> 3) ^ ((row >> 1) & 3);
    return ((row << 2) + g) * 8 + (kk & 7);
}

// ---------------- prep: pre-tile weights + embeddings (R8-proven) -----------
__global__ __launch_bounds__(256) void prep_kernel(
    const float* __restrict__ U_iou, const float* __restrict__ U_f,
    const float* __restrict__ W_iou, const float* __restrict__ W_f,
    const float* __restrict__ embed, const int* __restrict__ x,
    unsigned short* __restrict__ BW, unsigned short* __restrict__ AembT,
    unsigned int* __restrict__ slots)
{
    if (blockIdx.x == 0 && threadIdx.x < 16) slots[threadIdx.x * 16] = 0; // re-arm
    const int gBW = 4 * 5 * 17 * 256;   // 87040 granules of 8 shorts
    const int gAe = NS * 7 * 256;       // 456960
    int total = gBW + gAe;
    int stride = gridDim.x * blockDim.x;
    for (int gi = blockIdx.x * blockDim.x + threadIdx.x; gi < total; gi += stride) {
        unsigned short st[8];
        if (gi < gBW) {
            int gg = gi & 255, tile = gi >> 8;
            int row = gg >> 2, pos = gg & 3;
            int kk0 = (pos ^ ((row >> 1) & 3)) << 3;
            int c = tile % 17, t2 = tile / 17;
            int s = t2 % 5, g4 = t2 / 5;
            int j = s * 64 + row;
#pragma unroll
            for (int u = 0; u < 8; ++u) {
                int kk = kk0 + u; float v = 0.f;
                if (c < 7) {
                    int k = c * 32 + kk;
                    if (j < NH && k < NE)
                        v = (g4 < 3) ? W_iou[k * 900 + g4 * NH + j] : W_f[k * NH + j];
                } else {
                    int k = (c - 7) * 32 + kk;
                    if (j < NH && k < NH)
                        v = (g4 < 3) ? U_iou[k * 900 + g4 * NH + j] : U_f[k * NH + j];
                }
                st[u] = f2bf(v);
            }
            *(short8*)(BW + (size_t)tile * TS + (row * 4 + pos) * 8) = *(short8*)st;
        } else {
            int gi2 = gi - gBW;
            int gg = gi2 & 255, tile = gi2 >> 8;
            int row = gg >> 2, pos = gg & 3;
            int kk0 = (pos ^ ((row >> 1) & 3)) << 3;
            int c = tile % 7, node = tile / 7;
            int k0 = c * 32 + kk0;
            const float* er = embed + (size_t)x[node * NB + row] * NE;
#pragma unroll
            for (int u = 0; u < 8; ++u)
                st[u] = (k0 + u < NE) ? f2bf(er[k0 + u]) : (unsigned short)0;
            *(short8*)(AembT + (size_t)tile * TS + (row * 4 + pos) * 8) = *(short8*)st;
        }
    }
}

// chunk loop, 32-row half: A frags 2, B frags 4, 8 MFMA; A-stride templated
template<int NCH, int SA>
__device__ __forceinline__ void gemm2(f32x4 acc[4][2],
    const unsigned short* __restrict__ A, const unsigned short* __restrict__ B)
{
#pragma unroll
    for (int c = 0; c < NCH; ++c) {
        const unsigned short* At = A + c * SA;
        const unsigned short* Bt = B + c * TS;
        short8 a0 = *(const short8*)(At);
        short8 a1 = *(const short8*)(At + 512);
#pragma unroll
        for (int t = 0; t < 4; ++t) {
            short8 b = *(const short8*)(Bt + t * 512);
            acc[t][0] = __builtin_amdgcn_mfma_f32_16x16x32_bf16(a0, b, acc[t][0], 0, 0, 0);
            acc[t][1] = __builtin_amdgcn_mfma_f32_16x16x32_bf16(a1, b, acc[t][1], 0, 0, 0);
        }
    }
}
// full-M chunk loop (leaf): A frags 4, 16 MFMA (R7/R8-proven)
template<int NCH>
__device__ __forceinline__ void gemm_f(f32x4 acc[4][4],
    const unsigned short* __restrict__ A, const unsigned short* __restrict__ B)
{
#pragma unroll
    for (int c = 0; c < NCH; ++c) {
        const unsigned short* At = A + c * TS;
        const unsigned short* Bt = B + c * TS;
        short8 a0 = *(const short8*)(At);
        short8 a1 = *(const short8*)(At + 512);
        short8 a2 = *(const short8*)(At + 1024);
        short8 a3 = *(const short8*)(At + 1536);
#pragma unroll
        for (int t = 0; t < 4; ++t) {
            short8 b = *(const short8*)(Bt + t * 512);
            acc[t][0] = __builtin_amdgcn_mfma_f32_16x16x32_bf16(a0, b, acc[t][0], 0, 0, 0);
            acc[t][1] = __builtin_amdgcn_mfma_f32_16x16x32_bf16(a1, b, acc[t][1], 0, 0, 0);
            acc[t][2] = __builtin_amdgcn_mfma_f32_16x16x32_bf16(a2, b, acc[t][2], 0, 0, 0);
            acc[t][3] = __builtin_amdgcn_mfma_f32_16x16x32_bf16(a3, b, acc[t][3], 0, 0, 0);
        }
    }
}

// ---------------- grid sync: per-slot RMW-spin barriers (R7-proven core) ----
// Spin MUST be an RMW (atomicCAS) -- relaxed atomic-load spins never observe
// remote adds on this build (R1-R4). __threadfence release (wbl2) before
// arrival / acquire (inv) after departure carry H/C coherence (R7-proven).
// Per-slot counters (64B-padded) allow retiring blocks to PREPAY future
// slots without falsely satisfying the current one (a cumulative counter
// would race: prepays for slot k+1.. would unblock slot k early).
__device__ __forceinline__ void gbar(unsigned int* slot)
{
    __syncthreads();                       // all block stores vmcnt-drained
    if (threadIdx.x == 0) {
        __threadfence();                   // release: flush XCD L2 dirty lines
        atomicAdd(slot, 1u);
        int it = 0;
        while (atomicCAS(slot, 0xFFFFFFFFu, 0xFFFFFFFFu) < NBLK) {
            if (++it < 3) __builtin_amdgcn_s_sleep(8);
            else          __builtin_amdgcn_s_sleep(64);
            if (it > (1 << 17)) break;     // safety valve: never hang
        }
        __threadfence();                   // acquire: inv stale lines
    }
    __syncthreads();
}
// arrive at slot[from], prepay slots from+1..7, and let the block retire
__device__ __forceinline__ void gdepart(unsigned int* slots, int from)
{
    __syncthreads();
    if (threadIdx.x == 0) {
        __threadfence();
        for (int k = from; k < 8; ++k) atomicAdd(slots + k * 16, 1u);
    }
}

// ---------------- one internal-level task (p, s, half), 5 waves/sub ---------
__device__ __forceinline__ void level_body(int stid, int p, int s, int half,
    const unsigned short* __restrict__ AembT, const unsigned short* __restrict__ BW,
    const float* __restrict__ b_iou, const float* __restrict__ b_f,
    unsigned short* __restrict__ HbfT, unsigned short* __restrict__ Cg,
    unsigned short* sm)
{
    // Entry barrier: next round's LDS staging must not overlap stragglers
    // still reading sm in the previous round's epilogue. (Whole 640-block.)
    __syncthreads();

    int w = stid >> 6, lane = stid & 63, ln = lane & 15, quad = lane >> 4;
    int l = 2 * p + 1, r = 2 * p + 2;
    int bsel = (w < 4) ? w : 3;
    int gq = (quad ^ ((ln >> 1) & 3)) * 8;
    int offA = (half * 32 + ln) * 32 + gq;   // global A (emb tiles)
    int offL = ln * 32 + gq;                 // LDS A within half-tile
    int offB = ln * 32 + gq;

    // burst-stage: slots 0..9 Hl, 10..19 Hr, 20..21 Cl(2s,2s+1), 22..23 Cr
    for (int sidx = w; sidx < 24; sidx += 5) {
        const unsigned short* gsrc;
        if (sidx < 20) {
            int node = (sidx < 10) ? l : r;
            int tt = (sidx < 10) ? sidx : sidx - 10;
            gsrc = HbfT + ((size_t)node * 10 + tt) * TS + half * HTS;
        } else {
            int ii = sidx - 20;
            int node = (ii < 2) ? l : r;
            gsrc = Cg + ((size_t)node * 10 + 2 * s + (ii & 1)) * TS + half * HTS;
        }
        unsigned short* ldst = sm + sidx * HTS;
#pragma unroll
        for (int u = 0; u < 2; ++u)
            __builtin_amdgcn_global_load_lds(
                (const __attribute__((address_space(1))) unsigned short*)(gsrc + u * 512 + lane * 8),
                (__attribute__((address_space(3))) unsigned short*)(ldst + u * 512 + lane * 8),
                16, 0, 0);
    }

    f32x4 acc[4][2];
#pragma unroll
    for (int t = 0; t < 4; ++t)
#pragma unroll
        for (int q = 0; q < 2; ++q) acc[t][q] = (f32x4){0.f, 0.f, 0.f, 0.f};

    // emb contribution while the LDS DMA is in flight (A and B L2-warm)
    const unsigned short* Bsrc = BW + (size_t)(bsel * 5 + s) * 17 * TS;
    const unsigned short* Ae = AembT + (size_t)p * 7 * TS;
    gemm2<7, TS>(acc, Ae + offA, Bsrc + offB);

    __syncthreads();   // staging complete (vmcnt 0)

    const unsigned short* BH = Bsrc + 7 * TS + offB;
    if (w < 3) {
        gemm2<10, HTS>(acc, sm + offL, BH);             // Hl
        gemm2<10, HTS>(acc, sm + 10 * HTS + offL, BH);  // Hr
    } else if (w == 3) {
        gemm2<10, HTS>(acc, sm + offL, BH);
    } else {
        gemm2<10, HTS>(acc, sm + 10 * HTS + offL, BH);
    }

    // epilogue: smf aliases slots 0..5 (A consumed); C stays in slots 20..23
    float* smf = (float*)sm;
    for (int t = 0; t < 4; ++t) {
        __syncthreads();
#pragma unroll
        for (int ms = 0; ms < 2; ++ms)
#pragma unroll
            for (int rr = 0; rr < 4; ++rr)
                smf[w * 544 + (ms * 16 + quad * 4 + rr) * 17 + ln] = acc[t][ms][rr];
        __syncthreads();
        for (int idx2 = stid; idx2 < 512; idx2 += 320) {
            int mm = idx2 >> 4, n = idx2 & 15;
            int gm = half * 32 + mm;
            int jj = s * 64 + t * 16 + n;
            bool ok = jj < NH;
            float pi = smf[0 * 544 + mm * 17 + n] + (ok ? b_iou[jj] : 0.f);
            float po = smf[1 * 544 + mm * 17 + n] + (ok ? b_iou[NH + jj] : 0.f);
            float pu = smf[2 * 544 + mm * 17 + n] + (ok ? b_iou[2 * NH + jj] : 0.f);
            float bj = ok ? b_f[jj] : 0.f;
            float fl = sigmoidf_(smf[3 * 544 + mm * 17 + n] + bj);
            float fr = sigmoidf_(smf[4 * 544 + mm * 17 + n] + bj);
            int xr = (mm >> 1) & 3;
            int cel = (mm * 4 + ((((t & 1) * 2) + (n >> 3)) ^ xr)) * 8 + (n & 7);
            int ts2 = t >> 1;
            float cl = h2f(sm[(20 + ts2) * HTS + cel]);
            float cr = h2f(sm[(22 + ts2) * HTS + cel]);
            float cc = sigmoidf_(pi) * tanhf(pu) + fl * cl + fr * cr;
            float hh = sigmoidf_(po) * tanhf(cc);
            size_t tbase = ((size_t)p * 10 + (jj >> 5)) * TS + swz(gm, jj & 31);
            if (ok) Cg[tbase] = f2h(cc);               // plain: L2 write-back
            HbfT[tbase] = ok ? f2bf(hh) : (unsigned short)0;
        }
    }
}

// ---------------- leaf task (p, s): waves 0-2 of the sub compute i,o,u ------
__device__ __forceinline__ void leaf_body(int stid, int p, int s,
    const unsigned short* __restrict__ AembT, const unsigned short* __restrict__ BW,
    const float* __restrict__ b_iou,
    unsigned short* __restrict__ HbfT, unsigned short* __restrict__ Cg,
    unsigned short* sm)
{
    int w = stid >> 6, lane = stid & 63, ln = lane & 15, quad = lane >> 4;
    int off = ln * 32 + (quad ^ ((ln >> 1) & 3)) * 8;
    int wb = (w < 3) ? w : 0;
    const unsigned short* Bsrc = BW + (size_t)(wb * 5 + s) * 17 * TS;
    const unsigned short* Ae = AembT + (size_t)p * 7 * TS;

    f32x4 acc[4][4];
    if (w < 3) {
#pragma unroll
        for (int t = 0; t < 4; ++t)
#pragma unroll
            for (int q = 0; q < 4; ++q) acc[t][q] = (f32x4){0.f, 0.f, 0.f, 0.f};
        gemm_f<7>(acc, Ae + off, Bsrc + off);
    }

    float* tf = (float*)sm;   // [3][64][16] = 12 KB, aliases the sub's LDS
    for (int t = 0; t < 4; ++t) {
        __syncthreads();
        if (w < 3)
#pragma unroll
            for (int ms = 0; ms < 4; ++ms)
#pragma unroll
                for (int rr = 0; rr < 4; ++rr)
                    tf[(w * 64 + ms * 16 + quad * 4 + rr) * 16 + ln] = acc[t][ms][rr];
        __syncthreads();
        for (int idx2 = stid; idx2 < 1024; idx2 += 320) {
            int mm = idx2 >> 4, n = idx2 & 15;
            int jj = s * 64 + t * 16 + n;
            bool ok = jj < NH;
            float pi = tf[(0 * 64 + mm) * 16 + n] + (ok ? b_iou[jj] : 0.f);
            float po = tf[(1 * 64 + mm) * 16 + n] + (ok ? b_iou[NH + jj] : 0.f);
            float pu = tf[(2 * 64 + mm) * 16 + n] + (ok ? b_iou[2 * NH + jj] : 0.f);
            float cc = sigmoidf_(pi) * tanhf(pu);
            float hh = sigmoidf_(po) * tanhf(cc);
            size_t tbase = ((size_t)p * 10 + (jj >> 5)) * TS + swz(mm, jj & 31);
            if (ok) Cg[tbase] = f2h(cc);
            HbfT[tbase] = ok ? f2bf(hh) : (unsigned short)0;
        }
    }
}

// ---------------- fused tree: 256 blocks x 640 threads (2 tasks/block) ------
// Two 320-thread sub-blocks per block, each with a 48 KB LDS half -> 96 KB
// LDS/block, 1 block/CU on 256 CUs (co-resident by construction, R7-proven
// guarantee). 10 waves/CU doubles latency hiding; rounds drop 13 -> 10.
// launch_bounds(640,3) caps VGPR at 170 (measured 128) so 10 waves fit.
__global__ __launch_bounds__(640, 3) void tree_kernel(
    const unsigned short* __restrict__ AembT, const unsigned short* __restrict__ BW,
    const float* __restrict__ b_iou, const float* __restrict__ b_f,
    unsigned short* __restrict__ HbfT, unsigned short* __restrict__ Cg,
    const float* __restrict__ W_out, const float* __restrict__ b_out,
    float* __restrict__ outp, unsigned int* __restrict__ slots)
{
    __shared__ unsigned short sm[48 * HTS];   // 96 KB (2 x 48 KB halves)
    int bid = blockIdx.x;
    int tid = threadIdx.x;
    int sub = tid >= 320, stid = tid - (sub ? 320 : 0);
    unsigned short* smh = sm + (sub ? 24 * HTS : 0);

    // ---- leaf (level 7): 640 tasks, 2/block/round --------------------------
    for (int T2 = bid * 2; T2 < 640; T2 += NBLK * 2) {
        int T = T2 + sub;
        int xcd = T & 7, idx = T >> 3;
        leaf_body(stid, 127 + xcd * 16 + (idx & 15), idx >> 4,
                  AembT, BW, b_iou, HbfT, Cg, smh);
    }
    gbar(slots + 0 * 16);

    // ---- internal levels d=6..3: 80*(1<<(d-3)) tasks (even counts) ---------
#pragma unroll 1
    for (int d = 6; d >= 3; --d) {
        int sh2 = d - 3;
        int ntask = 80 << sh2;
        for (int T2 = bid * 2; T2 < ntask; T2 += NBLK * 2) {
            int T = T2 + sub;
            int xcd = T & 7, idx = T >> 3;
            int o = idx & ((1 << sh2) - 1);
            int rest = idx >> sh2;            // 0..9
            level_body(stid, (1 << d) - 1 + (xcd << sh2) + o, rest % 5, rest / 5,
                       AembT, BW, b_iou, b_f, HbfT, Cg, smh);
        }
        if (d > 3) gbar(slots + (7 - d) * 16);   // barriers 1,2,3
    }
    // barrier 4 (post-d3): blocks with no tail work retire + prepay
    if (bid >= 20) { gdepart(slots, 4); return; }
    gbar(slots + 4 * 16);

    // ---- tail levels d=2..0: 40/20/10 tasks, live blocks only --------------
    {   // d2: blocks 0..19
        int T = bid * 2 + sub, rest = T % 10;
        level_body(stid, 3 + T / 10, rest % 5, rest / 5,
                   AembT, BW, b_iou, b_f, HbfT, Cg, smh);
    }
    if (bid >= 10) { gdepart(slots, 5); return; }
    gbar(slots + 5 * 16);
    {   // d1: blocks 0..9
        int T = bid * 2 + sub, rest = T % 10;
        level_body(stid, 1 + T / 10, rest % 5, rest / 5,
                   AembT, BW, b_iou, b_f, HbfT, Cg, smh);
    }
    if (bid >= 5) { gdepart(slots, 6); return; }
    gbar(slots + 6 * 16);
    {   // d0: blocks 0..4
        int T = bid * 2 + sub, rest = T % 10;
        level_body(stid, 0, rest % 5, rest / 5,
                   AembT, BW, b_iou, b_f, HbfT, Cg, smh);
    }
    if (bid != 0) { gdepart(slots, 7); return; }
    gbar(slots + 7 * 16);

    // ---- root -> logits -> log_softmax (block 0, LDS-staged) ---------------
    {
        float* wsm = (float*)(sm + 20 * HTS); // after 40KB of root-H tiles
        for (int i = tid; i < 2560; i += 640) // 10 tiles x 256 granules
            *(short8*)(sm + i * 8) = *(const short8*)(HbfT + i * 8);
        for (int i = tid; i < 2 * NH; i += 640)
            wsm[i] = W_out[i];
        __syncthreads();
        if (tid < 64) {
            int b = tid;
            float l0 = 0.f, l1 = 0.f;
#pragma unroll 4
            for (int k = 0; k < NH; ++k) {
                float hk = bf2f(sm[(k >> 5) * TS + swz(b, k & 31)]);
                l0 += hk * wsm[2 * k];
                l1 += hk * wsm[2 * k + 1];
            }
            l0 += b_out[0];
            l1 += b_out[1];
            float mx = fmaxf(l0, l1);
            float lse = mx + logf(__expf(l0 - mx) + __expf(l1 - mx));
            outp[b * 2 + 0] = l0 - lse;
            outp[b * 2 + 1] = l1 - lse;
        }
    }
}

extern "C" void kernel_launch(void* const* d_in, const int* in_sizes, int n_in,
                              void* d_out, int out_size, void* d_ws, size_t ws_size,
                              hipStream_t stream)
{
    const int*   x     = (const int*)d_in[0];
    const float* embed = (const float*)d_in[3];
    const float* W_iou = (const float*)d_in[4];
    const float* U_iou = (const float*)d_in[5];
    const float* b_iou = (const float*)d_in[6];
    const float* W_f   = (const float*)d_in[7];
    const float* U_f   = (const float*)d_in[8];
    const float* b_f   = (const float*)d_in[9];
    const float* W_out = (const float*)d_in[10];
    const float* b_out = (const float*)d_in[11];

    char* ws = (char*)d_ws;
    unsigned short* HbfT  = (unsigned short*)(ws + 0);
    unsigned short* Cg    = (unsigned short*)(ws + 10444800);
    unsigned short* AembT = (unsigned short*)(ws + 20889600);
    unsigned short* BW    = (unsigned short*)(ws + 28200960);
    unsigned int*   slots = (unsigned int*)(ws + 29593600);

    prep_kernel<<<4096, 256, 0, stream>>>(U_iou, U_f, W_iou, W_f, embed, x,
                                          BW, AembT, slots);
    tree_kernel<<<NBLK, 640, 0, stream>>>(AembT, BW, b_iou, b_f, HbfT, Cg,
                                          W_out, b_out, (float*)d_out, slots);
}